// Round 10
// baseline (707.769 us; speedup 1.0000x reference)
//
#include <hip/hip_runtime.h>

typedef unsigned int uint;
typedef unsigned short ushort;
typedef unsigned long long u64;

typedef __attribute__((ext_vector_type(8))) short short8;
typedef __attribute__((ext_vector_type(4))) float floatx4;

// ---------------- helpers ----------------
__device__ inline ushort bf16rne(float v) {
  uint b = __float_as_uint(v);
  uint r = (b + 0x7fffu + ((b >> 16) & 1u)) >> 16;
  return (ushort)r;
}

__device__ inline void gl_lds16(const void* g, void* l) {
  __builtin_amdgcn_global_load_lds(
      (const __attribute__((address_space(1))) unsigned int*)g,
      (__attribute__((address_space(3))) unsigned int*)l, 16, 0, 0);
}

// ======================= chunk-seg-major global layouts =====================
//   xpadT: [cc 32][seg 4][spatial 66*66][8e]   (ci = cc*32 + seg*8 + e)
//   wT:    [off*32+cc][seg 4][co 1024][8e]
//   h:     [cc 32][seg 4][m 4096][8e]
//   wH:    [cc 32][seg 4][o 128][8e]
// Proven: seg-major LDS stage = 0 bank conflicts + coalesced wave staging.
// Conv structure history: simple dbuf 209us (r7) / B-in-regs 233 (r8) /
// counted-vmcnt 3-buf 220 (r9) -> r7 structure is the measured optimum;
// reverted to it here.

// ---------------- prep: x -> padded transposed bf16 hi/lo -------------------
__global__ __launch_bounds__(256) void prep_x(const float* __restrict__ x,
                                              ushort* __restrict__ xh,
                                              ushort* __restrict__ xl) {
  __shared__ float tile[8][512];
  int cc = blockIdx.x, sg = blockIdx.y, t = threadIdx.x;
  int ci0 = cc * 32 + sg * 8;
  size_t obase = (size_t)(cc * 4 + sg) * 4356;
  for (int it = 0; it < 4; ++it) {
    int s0 = blockIdx.z * 2048 + it * 512;
#pragma unroll
    for (int e = 0; e < 8; ++e) {
      tile[e][t] = x[(size_t)(ci0 + e) * 4096 + s0 + t];
      tile[e][t + 256] = x[(size_t)(ci0 + e) * 4096 + s0 + 256 + t];
    }
    __syncthreads();
#pragma unroll
    for (int w = 0; w < 2; ++w) {
      int sl = w * 256 + t;
      int s = s0 + sl;
      int y = s >> 6, xx = s & 63;
      short8 sh, slo;
#pragma unroll
      for (int e = 0; e < 8; ++e) {
        float v = tile[e][sl];
        ushort h2 = bf16rne(v);
        float hf = __uint_as_float((uint)h2 << 16);
        sh[e] = (short)h2;
        slo[e] = (short)bf16rne(v - hf);
      }
      size_t o = (obase + (size_t)(y + 1) * 66 + (xx + 1)) * 8;
      *(short8*)(xh + o) = sh;
      *(short8*)(xl + o) = slo;
    }
    __syncthreads();
  }
}

// ---------------- prep: conv_w[co][ci][3][3] -> wT chunk-seg-major ----------
__global__ __launch_bounds__(256) void prep_w(const float* __restrict__ w,
                                              ushort* __restrict__ wh,
                                              ushort* __restrict__ wl) {
  int cc = blockIdx.x, sg = blockIdx.y, t = threadIdx.x;
  int e = t & 7, col = t >> 3;
  int ci = cc * 32 + sg * 8 + e;
  for (int chunk = 0; chunk < 8; ++chunk) {
    int co = blockIdx.z * 256 + chunk * 32 + col;
    const float* src = w + ((size_t)co * 1024 + ci) * 9;
    float v[9];
#pragma unroll
    for (int o = 0; o < 9; ++o) v[o] = src[o];
#pragma unroll
    for (int off = 0; off < 9; ++off) {
      ushort h2 = bf16rne(v[off]);
      float hf = __uint_as_float((uint)h2 << 16);
      ushort l2 = bf16rne(v[off] - hf);
      size_t oi = ((size_t)(off * 32 + cc) * 4 + sg) * 8192 + (size_t)co * 8 + e;
      wh[oi] = h2;
      wl[oi] = l2;
    }
  }
}

// ---------------- prep: head weights -> wH chunk-seg-major + bias[128] ------
__global__ __launch_bounds__(256) void prep_head(
    const float* __restrict__ score_w, const float* __restrict__ loc_w,
    const float* __restrict__ score_b, const float* __restrict__ loc_b,
    ushort* __restrict__ wh, ushort* __restrict__ wl, float* __restrict__ bh) {
  int idx = blockIdx.x * 256 + threadIdx.x;  // < 131072
  int o = idx >> 10, ci = idx & 1023;
  float v = 0.f;
  if (o < 15) v = score_w[o * 1024 + ci];
  else if (o < 75) v = loc_w[(o - 15) * 1024 + ci];
  ushort h2 = bf16rne(v);
  float hf = __uint_as_float((uint)h2 << 16);
  int cc = ci >> 5, sg = (ci >> 3) & 3, e = ci & 7;
  size_t oi = ((size_t)(cc * 4 + sg) * 128 + o) * 8 + e;
  wh[oi] = h2;
  wl[oi] = bf16rne(v - hf);
  if (idx < 128) bh[idx] = (idx < 15) ? score_b[idx] : ((idx < 75) ? loc_b[idx - 15] : 0.f);
}

// ---------------- conv GEMM (im2col): round-7 double-buffer (209us) ---------
// M=4096, N=1024 (BN=64/block), K=9216. Tile 128x64, 256 threads (4 waves),
// 2 x 24KB LDS buffers = 48KB -> 2 blocks/CU. K-accumulation order
// BIT-IDENTICAL to round 0 (sequential chunks, hh/hl/lh MFMA order).
// LDS seg-major [4 k-octets][rows][16B]: 0 bank conflicts (measured).
// Globals chunk-seg-major: each wave's stage reads 1KB contiguous.
__global__ __launch_bounds__(256, 1) void gemm_conv(
    const ushort* __restrict__ Ahi, const ushort* __restrict__ Alo,
    const ushort* __restrict__ Bhi, const ushort* __restrict__ Blo,
    const float* __restrict__ bias, ushort* __restrict__ outHi,
    ushort* __restrict__ outLo) {
  constexpr int NC = 288;
  constexpr int ASEC = 128 * 32;             // ushorts per A section (8KB)
  constexpr int BSEC = 64 * 32;              // ushorts per B section (4KB)
  constexpr int BUFU = 2 * ASEC + 2 * BSEC;  // 24 KB per buffer
  __shared__ ushort sm[2 * BUFU];            // 48 KB -> 2 blocks/CU
  const int t = threadIdx.x;
  const int m0 = blockIdx.x * 128;
  const int n0 = blockIdx.y * 64;

  const int lane = t & 63, wv = t >> 6;
  const int wm = (wv & 1) * 64, wn = (wv >> 1) * 32;
  const int rA = wm + (lane & 15);
  const int rB = wn + (lane & 15);
  const int segA = (lane >> 4) * 2048;  // A seg region base (bytes)
  const int segB = (lane >> 4) * 1024;  // B seg region base (bytes)

  auto stage = [&](int c, int bufIdx) {
    ushort* secAh = sm + bufIdx * BUFU;
    ushort* secAl = secAh + ASEC;
    ushort* secBh = secAl + ASEC;
    ushort* secBl = secBh + BSEC;
    int off = c >> 5, cc = c & 31;
    int oy = off / 3, ox = off - 3 * oy;
    // A: 512 slots, seg-major (row = L&127, seg = L>>7); wave = 1KB contig
#pragma unroll
    for (int q = 0; q < 2; ++q) {
      int L = t + 256 * q;
      int row = L & 127, seg = L >> 7;
      int m = m0 + row, y = m >> 6, xq = m & 63;
      size_t aoff = ((size_t)(cc * 4 + seg) * 4356 + (y + oy) * 66 + (xq + ox)) * 16;
      gl_lds16((const char*)Ahi + aoff, (char*)secAh + L * 16);
      gl_lds16((const char*)Alo + aoff, (char*)secAl + L * 16);
    }
    // B: 256 slots, seg-major (row = L&63, seg = L>>6); wave = 1KB contig
    {
      int L = t;
      int row = L & 63, seg = L >> 6;
      size_t boff = (((size_t)(off * 32 + cc) * 4 + seg) * 1024 + (n0 + row)) * 16;
      gl_lds16((const char*)Bhi + boff, (char*)secBh + L * 16);
      gl_lds16((const char*)Blo + boff, (char*)secBl + L * 16);
    }
  };

  floatx4 acc[4][2];
#pragma unroll
  for (int i = 0; i < 4; ++i)
#pragma unroll
    for (int j = 0; j < 2; ++j) acc[i][j] = (floatx4){0.f, 0.f, 0.f, 0.f};

  auto compute = [&](const ushort* sb) {
    const char* cAh = (const char*)sb;
    const char* cAl = (const char*)(sb + ASEC);
    const char* cBh = (const char*)(sb + 2 * ASEC);
    const char* cBl = (const char*)(sb + 2 * ASEC + BSEC);
    short8 ah[4], al[4], bh2[2], bl2[2];
#pragma unroll
    for (int i = 0; i < 4; ++i) {
      int pa = segA + (rA + 16 * i) * 16;
      ah[i] = *(const short8*)(cAh + pa);
      al[i] = *(const short8*)(cAl + pa);
    }
#pragma unroll
    for (int j = 0; j < 2; ++j) {
      int pb = segB + (rB + 16 * j) * 16;
      bh2[j] = *(const short8*)(cBh + pb);
      bl2[j] = *(const short8*)(cBl + pb);
    }
#pragma unroll
    for (int i = 0; i < 4; ++i)
#pragma unroll
      for (int j = 0; j < 2; ++j) {
        acc[i][j] = __builtin_amdgcn_mfma_f32_16x16x32_bf16(ah[i], bh2[j], acc[i][j], 0, 0, 0);
        acc[i][j] = __builtin_amdgcn_mfma_f32_16x16x32_bf16(ah[i], bl2[j], acc[i][j], 0, 0, 0);
        acc[i][j] = __builtin_amdgcn_mfma_f32_16x16x32_bf16(al[i], bh2[j], acc[i][j], 0, 0, 0);
      }
  };

  stage(0, 0);
  for (int kc = 0; kc < NC; ++kc) {
    __syncthreads();  // staged chunk kc landed; prev compute's reads done
    if (kc + 1 < NC) stage(kc + 1, (kc + 1) & 1);  // overlap with compute
    compute(sm + (kc & 1) * BUFU);
  }

#pragma unroll
  for (int i = 0; i < 4; ++i)
#pragma unroll
    for (int j = 0; j < 2; ++j) {
      int nn = n0 + wn + 16 * j + (lane & 15);
      float bv = bias[nn];
#pragma unroll
      for (int r = 0; r < 4; ++r) {
        int mm = m0 + wm + 16 * i + (lane >> 4) * 4 + r;  // C: row=(lane>>4)*4+reg
        float v = fmaxf(acc[i][j][r] + bv, 0.f);
        ushort h2 = bf16rne(v);
        float hf = __uint_as_float((uint)h2 << 16);
        ushort l2 = bf16rne(v - hf);
        int cc = nn >> 5, sg = (nn >> 3) & 3, e = nn & 7;
        size_t ho = ((size_t)(cc * 4 + sg) * 4096 + mm) * 8 + e;
        outHi[ho] = h2;
        outLo[ho] = l2;
      }
    }
}

// ---------------- head GEMM: A-LDS + B-regs (round 8, kept: it helped) ------
template <int BM, int BN>
__global__ __launch_bounds__(256, 1) void gemm_head(
    const ushort* __restrict__ Ahi, const ushort* __restrict__ Alo,
    const ushort* __restrict__ Bhi, const ushort* __restrict__ Blo,
    const float* __restrict__ bias, int nChunks, float* __restrict__ outRaw) {
  constexpr int ASEC = BM * 32;
  constexpr int BUFU = 2 * ASEC;
  constexpr int WM = (BM >= 128) ? 2 : 1;
  constexpr int WN = 4 / WM;
  constexpr int MI = (BM / WM) / 16;
  constexpr int NJ = (BN / WN) / 16;
  __shared__ ushort sm[2 * BUFU];
  const int t = threadIdx.x;
  const int m0 = blockIdx.x * BM;
  const int n0 = blockIdx.y * BN;

  const int lane = t & 63, wv = t >> 6;
  const int wm = (wv % WM) * (BM / WM);
  const int wn = (wv / WM) * (BN / WN);
  const int rA = wm + (lane & 15);
  const int segA = (lane >> 4) * (BM * 16);

  auto stage = [&](int c, int bufIdx) {
    ushort* secAh = sm + bufIdx * BUFU;
    ushort* secAl = secAh + ASEC;
    for (int L = t; L < BM * 4; L += 256) {
      int row = L % BM, seg = L / BM;
      size_t aoff = ((size_t)(c * 4 + seg) * 4096 + (m0 + row)) * 16;
      gl_lds16((const char*)Ahi + aoff, (char*)secAh + L * 16);
      gl_lds16((const char*)Alo + aoff, (char*)secAl + L * 16);
    }
  };

  auto loadB = [&](int c, short8* bh, short8* bl) {
    int sg = lane >> 4;
#pragma unroll
    for (int j = 0; j < NJ; ++j) {
      int co = n0 + wn + (lane & 15) + 16 * j;
      size_t boff = (((size_t)(c * 4 + sg)) * 128 + co) * 16;
      bh[j] = *(const short8*)((const char*)Bhi + boff);
      bl[j] = *(const short8*)((const char*)Blo + boff);
    }
  };

  floatx4 acc[MI][NJ];
#pragma unroll
  for (int i = 0; i < MI; ++i)
#pragma unroll
    for (int j = 0; j < NJ; ++j) acc[i][j] = (floatx4){0.f, 0.f, 0.f, 0.f};

  auto compute = [&](const ushort* sb, const short8* bh2, const short8* bl2) {
    const char* cAh = (const char*)sb;
    const char* cAl = (const char*)(sb + ASEC);
    short8 ah[MI], al[MI];
#pragma unroll
    for (int i = 0; i < MI; ++i) {
      int pa = segA + (rA + 16 * i) * 16;
      ah[i] = *(const short8*)(cAh + pa);
      al[i] = *(const short8*)(cAl + pa);
    }
#pragma unroll
    for (int i = 0; i < MI; ++i)
#pragma unroll
      for (int j = 0; j < NJ; ++j) {
        acc[i][j] = __builtin_amdgcn_mfma_f32_16x16x32_bf16(ah[i], bh2[j], acc[i][j], 0, 0, 0);
        acc[i][j] = __builtin_amdgcn_mfma_f32_16x16x32_bf16(ah[i], bl2[j], acc[i][j], 0, 0, 0);
        acc[i][j] = __builtin_amdgcn_mfma_f32_16x16x32_bf16(al[i], bh2[j], acc[i][j], 0, 0, 0);
      }
  };

  short8 b0h[NJ], b0l[NJ], b1h[NJ], b1l[NJ];
  stage(0, 0);
  loadB(0, b0h, b0l);
  for (int kc = 0; kc < nChunks; kc += 2) {
    __syncthreads();
    if (kc + 1 < nChunks) { stage(kc + 1, 1); loadB(kc + 1, b1h, b1l); }
    compute(sm, b0h, b0l);
    __syncthreads();
    if (kc + 2 < nChunks) { stage(kc + 2, 0); loadB(kc + 2, b0h, b0l); }
    compute(sm + BUFU, b1h, b1l);
  }

#pragma unroll
  for (int i = 0; i < MI; ++i)
#pragma unroll
    for (int j = 0; j < NJ; ++j) {
      int nn = n0 + wn + 16 * j + (lane & 15);
      float bv = bias[nn];
#pragma unroll
      for (int r = 0; r < 4; ++r) {
        int mm = m0 + wm + 16 * i + (lane >> 4) * 4 + r;
        outRaw[(size_t)mm * 128 + nn] = acc[i][j][r] + bv;
      }
    }
}

// ---------------- decode + key + histogram ----------------------------------
__global__ __launch_bounds__(256) void decode_k(const float* __restrict__ raw,
                                                float* __restrict__ scores,
                                                float4* __restrict__ boxes,
                                                uint* __restrict__ key32,
                                                uint* __restrict__ hist) {
  int i = blockIdx.x * 256 + threadIdx.x;  // exactly 61440
  int m = i / 15, a = i - m * 15;
  int y = m >> 6, x = m & 63;
  const float* rp = raw + (size_t)m * 128;
  float logit = rp[a];
  float dx = rp[15 + 4 * a], dy = rp[16 + 4 * a];
  float dw = rp[17 + 4 * a], dh = rp[18 + 4 * a];
  int rr = a / 5, ss = a - rr * 5;
  float sc5 = (float)(2 << ss);
  float W = ((rr == 0) ? 23.f : (rr == 1) ? 16.f : 11.f) * sc5;
  float H = ((rr == 0) ? 12.f : (rr == 1) ? 16.f : 22.f) * sc5;
  float aw = W - 1.f, ah = H - 1.f;
  float ax = x * 16.f + 7.5f, ay = y * 16.f + 7.5f;
  float ox = dx * aw + ax, oyc = dy * ah + ay;
  float ow = expf(fminf(dw, 4.14f)) * aw * 0.5f;
  float oh = expf(fminf(dh, 4.14f)) * ah * 0.5f;
  float x1 = fminf(fmaxf(ox - ow, 0.f), 1023.f);
  float y1 = fminf(fmaxf(oyc - oh, 0.f), 1023.f);
  float x2 = fminf(fmaxf(ox + ow, 0.f), 1023.f);
  float y2 = fminf(fmaxf(oyc + oh, 0.f), 1023.f);
  bool inval = ((x2 - x1) < 16.f) || ((y2 - y1) < 16.f);
  float sc = inval ? -1.f : (1.f / (1.f + expf(-logit)));
  scores[i] = sc;
  boxes[i] = inval ? make_float4(-1.f, -1.f, -1.f, -1.f) : make_float4(x1, y1, x2, y2);
  uint kb = __float_as_uint(sc);
  uint key = (kb & 0x80000000u) ? ~kb : (kb | 0x80000000u);
  key32[i] = key;
  atomicAdd(&hist[key >> 16], 1u);
}

// ---------------- seg_sum: coalesced 256-entry segment sums of hist ---------
__global__ __launch_bounds__(256) void seg_sum(const uint* __restrict__ hist,
                                               uint* __restrict__ segsum) {
  __shared__ uint red[256];
  int b = blockIdx.x, t = threadIdx.x;
  red[t] = hist[b * 256 + t];
  __syncthreads();
  for (int d = 128; d > 0; d >>= 1) {
    if (t < d) red[t] += red[t + d];
    __syncthreads();
  }
  if (t == 0) segsum[b] = red[0];
}

// ---------------- find 16-bit prefix threshold for top-6000 -----------------
__global__ __launch_bounds__(256) void find_t16(const uint* __restrict__ hist,
                                                const uint* __restrict__ segsum,
                                                uint* __restrict__ selT) {
  __shared__ uint ps[256];
  __shared__ int segS;
  int t = threadIdx.x;
  ps[t] = segsum[t];
  __syncthreads();
  for (int d = 1; d < 256; d <<= 1) {
    uint v = ps[t] + ((t + d < 256) ? ps[t + d] : 0u);
    __syncthreads();
    ps[t] = v;
    __syncthreads();
  }
  if (ps[t] >= 6000u && (t == 255 || ps[t + 1] < 6000u)) segS = t;
  __syncthreads();
  int sg = segS;
  uint base = (sg == 255) ? 0u : ps[sg + 1];
  uint h2 = hist[sg * 256 + t];
  __syncthreads();
  ps[t] = h2;
  __syncthreads();
  for (int d = 1; d < 256; d <<= 1) {
    uint v = ps[t] + ((t + d < 256) ? ps[t + d] : 0u);
    __syncthreads();
    ps[t] = v;
    __syncthreads();
  }
  if (base + ps[t] >= 6000u && (t == 255 || base + ps[t + 1] < 6000u))
    *selT = (uint)(sg * 256 + t);
}

// ---------------- gather candidates (prefix >= T16) -------------------------
__global__ __launch_bounds__(256) void gather_k(const uint* __restrict__ key32,
                                                const uint* __restrict__ selT,
                                                uint* __restrict__ cnt,
                                                u64* __restrict__ cand) {
  int i = blockIdx.x * 256 + threadIdx.x;  // exactly 61440
  uint T = *selT;
  uint k = key32[i];
  if ((k >> 16) >= T) {
    uint pos = atomicAdd(cnt, 1u);
    if (pos < 8192) cand[pos] = ((u64)k << 32) | (u64)(~(uint)i);
  }
}

// ---------------- single-block bitonic sort (desc) + gather top-6000 --------
__global__ __launch_bounds__(1024) void sort_gather(
    const u64* __restrict__ cand, const uint* __restrict__ cnt,
    const float* __restrict__ scores, const float4* __restrict__ boxes,
    float* __restrict__ sortedS, float4* __restrict__ sortedB) {
  extern __shared__ u64 sk[];  // 8192 * 8 = 64 KB
  int t = threadIdx.x;
  int C = (int)*cnt;
  if (C > 8192) C = 8192;
  for (int j = t; j < 8192; j += 1024) sk[j] = (j < C) ? cand[j] : 0ull;
  __syncthreads();
  for (int k = 2; k <= 8192; k <<= 1) {
    for (int j2 = k >> 1; j2 > 0; j2 >>= 1) {
      for (int p = t; p < 4096; p += 1024) {
        int i = ((p & ~(j2 - 1)) << 1) | (p & (j2 - 1));
        int ix = i | j2;
        u64 a = sk[i], b = sk[ix];
        bool ddir = (i & k) != 0;
        if ((a < b) != ddir) { sk[i] = b; sk[ix] = a; }
      }
      __syncthreads();
    }
  }
  for (int j = t; j < 6016; j += 1024) {
    if (j < 6000) {
      u64 key = sk[j];
      uint idx = ~(uint)(key & 0xffffffffu);
      sortedS[j] = scores[idx];
      sortedB[j] = boxes[idx];
    } else {
      sortedS[j] = -1.f;
      sortedB[j] = make_float4(0.f, 0.f, 0.f, 0.f);
    }
  }
}

// ---------------- IoU suppression bitmask: mask[row][128 u64 words] ---------
__global__ __launch_bounds__(64) void iou_mask(const float4* __restrict__ boxes,
                                               u64* __restrict__ mask) {
  __shared__ float cx1[64], cy1[64], cx2[64], cy2[64], car[64];
  int bi = blockIdx.x, bj = blockIdx.y, t = threadIdx.x;
  float4 cb = boxes[bj * 64 + t];
  cx1[t] = cb.x; cy1[t] = cb.y; cx2[t] = cb.z; cy2[t] = cb.w;
  car[t] = (cb.z - cb.x) * (cb.w - cb.y);
  __syncthreads();
  int r = bi * 64 + t;
  float4 rb = boxes[r];
  float ra = (rb.z - rb.x) * (rb.w - rb.y);
  u64 wd = 0;
#pragma unroll 8
  for (int j = 0; j < 64; ++j) {
    float iw = fmaxf(fminf(rb.z, cx2[j]) - fmaxf(rb.x, cx1[j]), 0.f);
    float ih = fmaxf(fminf(rb.w, cy2[j]) - fmaxf(rb.y, cy1[j]), 0.f);
    float inter = iw * ih;
    float iou = inter / (ra + car[j] - inter + 1e-12f);
    if (iou > 0.7f && r != bj * 64 + j) wd |= (1ull << j);
  }
  mask[(size_t)r * 128 + bj] = wd;
}

// ---------------- serial NMS scan (1 wave), 2-slot pipelined row loads ------
__global__ __launch_bounds__(64) void nms_scan(const u64* __restrict__ mask,
                                               const float* __restrict__ sortedS,
                                               const float4* __restrict__ sortedB,
                                               float* __restrict__ out) {
  __shared__ int klist[300];
  int lane = threadIdx.x;
  u64 Sx = 0, Sy = 0;  // lane l owns suppression words 2l and 2l+1
  for (int w2 = 0; w2 < 94; ++w2) {
    bool neg = sortedS[w2 * 64 + lane] < 0.f;
    u64 m2 = __ballot(neg);
    if ((w2 >> 1) == lane) { if (w2 & 1) Sy = m2; else Sx = m2; }
  }
  int count = 0;
  for (int w2 = 0; w2 < 94; ++w2) {
    u64 cur = __shfl((w2 & 1) ? Sy : Sx, w2 >> 1);
    u64 rem = ~cur;
    if (w2 == 93) rem &= (1ull << 48) - 1;  // rows 6000..6015 are pad
    if (!rem) continue;
    int bA = __builtin_ctzll(rem);
    ulonglong2 vA = ((const ulonglong2*)(mask + (size_t)(w2 * 64 + bA) * 128))[lane];
    int bB;
    ulonglong2 vB;
    for (;;) {
      {  // --- slot A current, speculate into slot B ---
        u64 remS = (bA == 63) ? 0ull : (rem & (~0ull << (bA + 1)));
        bB = remS ? __builtin_ctzll(remS) : -1;
        if (bB >= 0)
          vB = ((const ulonglong2*)(mask + (size_t)(w2 * 64 + bB) * 128))[lane];
        if (lane == 0) klist[count] = w2 * 64 + bA;
        count++;
        if (count == 300) goto done;
        Sx |= vA.x;
        Sy |= vA.y;
        u64 cur2 = __shfl((w2 & 1) ? Sy : Sx, w2 >> 1);
        rem = remS & ~cur2;
        if (!rem) break;
        int bn = __builtin_ctzll(rem);
        if (bn != bB) {  // misspeculation: reissue
          bB = bn;
          vB = ((const ulonglong2*)(mask + (size_t)(w2 * 64 + bB) * 128))[lane];
        }
      }
      {  // --- slot B current, speculate into slot A ---
        u64 remS = (bB == 63) ? 0ull : (rem & (~0ull << (bB + 1)));
        bA = remS ? __builtin_ctzll(remS) : -1;
        if (bA >= 0)
          vA = ((const ulonglong2*)(mask + (size_t)(w2 * 64 + bA) * 128))[lane];
        if (lane == 0) klist[count] = w2 * 64 + bB;
        count++;
        if (count == 300) goto done;
        Sx |= vB.x;
        Sy |= vB.y;
        u64 cur2 = __shfl((w2 & 1) ? Sy : Sx, w2 >> 1);
        rem = remS & ~cur2;
        if (!rem) break;
        int bn = __builtin_ctzll(rem);
        if (bn != bA) {  // misspeculation: reissue
          bA = bn;
          vA = ((const ulonglong2*)(mask + (size_t)(w2 * 64 + bA) * 128))[lane];
        }
      }
    }
  }
done:
  __syncthreads();
  for (int j = lane; j < 300; j += 64) {
    float s;
    float4 bb;
    if (j < count) {
      int i = klist[j];
      s = sortedS[i];
      bb = sortedB[i];
    } else {
      s = -1.f;
      bb = make_float4(-1.f, -1.f, -1.f, -1.f);
    }
    out[j * 5 + 0] = s;
    out[j * 5 + 1] = bb.x;
    out[j * 5 + 2] = bb.y;
    out[j * 5 + 3] = bb.z;
    out[j * 5 + 4] = bb.w;
  }
}

// ---------------- workspace layout (bytes) ----------------------------------
constexpr size_t O_XH = 0;                // 8,921,088   xpadT hi
constexpr size_t O_XL = 8921088;          // 8,921,088   xpadT lo
constexpr size_t O_WTH = 17842176;        // 18,874,368  wT hi
constexpr size_t O_WTL = 36716544;        // 18,874,368  wT lo
constexpr size_t O_HH = 55590912;         // 8,388,608   h hi
constexpr size_t O_HL = 63979520;         // 8,388,608   h lo
constexpr size_t O_WHH = 72368128;        // 262,144     head w hi
constexpr size_t O_WHL = 72630272;        // 262,144     head w lo
constexpr size_t O_BHD = 72892416;        // 512         head bias
constexpr size_t O_SC = 72892928;         // 245,760     scores
constexpr size_t O_BX = 73138688;         // 983,040     boxes (float4)
constexpr size_t O_KEY = 74121728;        // 245,760     key32
constexpr size_t O_HIST = 74367488;       // 262,144     histogram
constexpr size_t O_CNT = 74629632;        // 256         atomic counter
constexpr size_t O_CAND = 74629888;       // 65,536      candidates
constexpr size_t O_SELT = 74695424;       // 256         T16
constexpr size_t O_SS = 74695680;         // 24,064      sorted scores [6016]
constexpr size_t O_SB = 74719744;         // 96,256      sorted boxes  [6016]
// aliases (regions dead by the time these are written):
constexpr size_t O_RAW = 0;               // 2,097,152  raw head out (aliases xpadT, dead after conv GEMM)
constexpr size_t O_MASK = 17842176;       // 6,160,384  NMS mask (aliases wT, dead after conv GEMM)
constexpr size_t O_SEG = 24002560;        // 1,024      segsum (aliases wT tail)
// total distinct footprint ~74.8 MB

extern "C" void kernel_launch(void* const* d_in, const int* in_sizes, int n_in,
                              void* d_out, int out_size, void* d_ws,
                              size_t ws_size, hipStream_t stream) {
  (void)in_sizes; (void)n_in; (void)out_size; (void)ws_size;
  const float* x = (const float*)d_in[1];
  const float* conv_w = (const float*)d_in[2];
  const float* conv_b = (const float*)d_in[3];
  const float* score_w = (const float*)d_in[4];
  const float* score_b = (const float*)d_in[5];
  const float* loc_w = (const float*)d_in[6];
  const float* loc_b = (const float*)d_in[7];
  float* out = (float*)d_out;
  char* ws = (char*)d_ws;

  ushort* xh = (ushort*)(ws + O_XH);
  ushort* xl = (ushort*)(ws + O_XL);
  ushort* wTh = (ushort*)(ws + O_WTH);
  ushort* wTl = (ushort*)(ws + O_WTL);
  ushort* hh = (ushort*)(ws + O_HH);
  ushort* hl = (ushort*)(ws + O_HL);
  ushort* wHh = (ushort*)(ws + O_WHH);
  ushort* wHl = (ushort*)(ws + O_WHL);
  float* biasH = (float*)(ws + O_BHD);
  float* raw = (float*)(ws + O_RAW);
  float* scores = (float*)(ws + O_SC);
  float4* boxes = (float4*)(ws + O_BX);
  uint* key32 = (uint*)(ws + O_KEY);
  uint* hist = (uint*)(ws + O_HIST);
  uint* cnt = (uint*)(ws + O_CNT);
  u64* cand = (u64*)(ws + O_CAND);
  uint* selT = (uint*)(ws + O_SELT);
  float* sortedS = (float*)(ws + O_SS);
  float4* sortedB = (float4*)(ws + O_SB);
  u64* mask = (u64*)(ws + O_MASK);
  uint* segsum = (uint*)(ws + O_SEG);

  // zero the padded-input borders (whole buffer) and histogram+counter
  hipMemsetAsync(ws + O_XH, 0, 2 * 8921088, stream);
  hipMemsetAsync(ws + O_HIST, 0, 262144 + 256, stream);

  prep_x<<<dim3(32, 4, 2), 256, 0, stream>>>(x, xh, xl);
  prep_w<<<dim3(32, 4, 4), 256, 0, stream>>>(conv_w, wTh, wTl);
  prep_head<<<512, 256, 0, stream>>>(score_w, loc_w, score_b, loc_b, wHh, wHl, biasH);

  // conv: M=4096, N=1024, K=9216 -> h (relu, bf16 hi/lo); tile 128x64,
  // grid (32,16)=512 blocks -> 2 blocks/CU; round-7 double-buffer (209us)
  gemm_conv<<<dim3(32, 16), 256, 0, stream>>>(xh, xl, wTh, wTl, conv_b, hh, hl);
  // heads: M=4096, N=128(pad), K=1024 -> raw f32; tile 32x128, 128 blocks
  gemm_head<32, 128><<<dim3(128, 1), 256, 0, stream>>>(hh, hl, wHh, wHl, biasH,
                                                       32, raw);

  decode_k<<<240, 256, 0, stream>>>(raw, scores, boxes, key32, hist);
  seg_sum<<<256, 256, 0, stream>>>(hist, segsum);
  find_t16<<<1, 256, 0, stream>>>(hist, segsum, selT);
  gather_k<<<240, 256, 0, stream>>>(key32, selT, cnt, cand);
  sort_gather<<<1, 1024, 65536, stream>>>(cand, cnt, scores, boxes, sortedS, sortedB);
  iou_mask<<<dim3(94, 94), 64, 0, stream>>>(sortedB, mask);
  nms_scan<<<1, 64, 0, stream>>>(mask, sortedS, sortedB, out);
}

// Round 11
// 699.537 us; speedup vs baseline: 1.0118x; 1.0118x over previous
//
#include <hip/hip_runtime.h>

typedef unsigned int uint;
typedef unsigned short ushort;
typedef unsigned long long u64;

typedef __attribute__((ext_vector_type(8))) short short8;
typedef __attribute__((ext_vector_type(4))) float floatx4;

// ---------------- helpers ----------------
__device__ inline ushort bf16rne(float v) {
  uint b = __float_as_uint(v);
  uint r = (b + 0x7fffu + ((b >> 16) & 1u)) >> 16;
  return (ushort)r;
}

__device__ inline void gl_lds16(const void* g, void* l) {
  __builtin_amdgcn_global_load_lds(
      (const __attribute__((address_space(1))) unsigned int*)g,
      (__attribute__((address_space(3))) unsigned int*)l, 16, 0, 0);
}

// ======================= chunk-seg-major global layouts =====================
//   xpadT: [cc 32][seg 4][spatial 66*66][8e]   (ci = cc*32 + seg*8 + e)
//   wT:    [off*32+cc][seg 4][co 1024][8e]
//   h:     [cc 32][seg 4][m 4096][8e]
//   wH:    [cc 32][seg 4][o 128][8e]
// Proven: seg-major LDS stage = 0 bank conflicts + coalesced wave staging.
// Conv structure history: simple dbuf 209-212us (r7/r10, BEST) / B-in-regs
// 233 (r8) / counted-vmcnt 3-buf 220 (r9). Frozen at r7 structure.

// ---------------- prep: x -> padded transposed bf16 hi/lo -------------------
__global__ __launch_bounds__(256) void prep_x(const float* __restrict__ x,
                                              ushort* __restrict__ xh,
                                              ushort* __restrict__ xl) {
  __shared__ float tile[8][512];
  int cc = blockIdx.x, sg = blockIdx.y, t = threadIdx.x;
  int ci0 = cc * 32 + sg * 8;
  size_t obase = (size_t)(cc * 4 + sg) * 4356;
  for (int it = 0; it < 4; ++it) {
    int s0 = blockIdx.z * 2048 + it * 512;
#pragma unroll
    for (int e = 0; e < 8; ++e) {
      tile[e][t] = x[(size_t)(ci0 + e) * 4096 + s0 + t];
      tile[e][t + 256] = x[(size_t)(ci0 + e) * 4096 + s0 + 256 + t];
    }
    __syncthreads();
#pragma unroll
    for (int w = 0; w < 2; ++w) {
      int sl = w * 256 + t;
      int s = s0 + sl;
      int y = s >> 6, xx = s & 63;
      short8 sh, slo;
#pragma unroll
      for (int e = 0; e < 8; ++e) {
        float v = tile[e][sl];
        ushort h2 = bf16rne(v);
        float hf = __uint_as_float((uint)h2 << 16);
        sh[e] = (short)h2;
        slo[e] = (short)bf16rne(v - hf);
      }
      size_t o = (obase + (size_t)(y + 1) * 66 + (xx + 1)) * 8;
      *(short8*)(xh + o) = sh;
      *(short8*)(xl + o) = slo;
    }
    __syncthreads();
  }
}

// ---------------- prep: conv_w[co][ci][3][3] -> wT chunk-seg-major ----------
__global__ __launch_bounds__(256) void prep_w(const float* __restrict__ w,
                                              ushort* __restrict__ wh,
                                              ushort* __restrict__ wl) {
  int cc = blockIdx.x, sg = blockIdx.y, t = threadIdx.x;
  int e = t & 7, col = t >> 3;
  int ci = cc * 32 + sg * 8 + e;
  for (int chunk = 0; chunk < 8; ++chunk) {
    int co = blockIdx.z * 256 + chunk * 32 + col;
    const float* src = w + ((size_t)co * 1024 + ci) * 9;
    float v[9];
#pragma unroll
    for (int o = 0; o < 9; ++o) v[o] = src[o];
#pragma unroll
    for (int off = 0; off < 9; ++off) {
      ushort h2 = bf16rne(v[off]);
      float hf = __uint_as_float((uint)h2 << 16);
      ushort l2 = bf16rne(v[off] - hf);
      size_t oi = ((size_t)(off * 32 + cc) * 4 + sg) * 8192 + (size_t)co * 8 + e;
      wh[oi] = h2;
      wl[oi] = l2;
    }
  }
}

// ---------------- prep: head weights -> wH chunk-seg-major + bias[128] ------
__global__ __launch_bounds__(256) void prep_head(
    const float* __restrict__ score_w, const float* __restrict__ loc_w,
    const float* __restrict__ score_b, const float* __restrict__ loc_b,
    ushort* __restrict__ wh, ushort* __restrict__ wl, float* __restrict__ bh) {
  int idx = blockIdx.x * 256 + threadIdx.x;  // < 131072
  int o = idx >> 10, ci = idx & 1023;
  float v = 0.f;
  if (o < 15) v = score_w[o * 1024 + ci];
  else if (o < 75) v = loc_w[(o - 15) * 1024 + ci];
  ushort h2 = bf16rne(v);
  float hf = __uint_as_float((uint)h2 << 16);
  int cc = ci >> 5, sg = (ci >> 3) & 3, e = ci & 7;
  size_t oi = ((size_t)(cc * 4 + sg) * 128 + o) * 8 + e;
  wh[oi] = h2;
  wl[oi] = bf16rne(v - hf);
  if (idx < 128) bh[idx] = (idx < 15) ? score_b[idx] : ((idx < 75) ? loc_b[idx - 15] : 0.f);
}

// ---------------- conv GEMM (im2col): round-7 double-buffer (209us) ---------
// M=4096, N=1024 (BN=64/block), K=9216. Tile 128x64, 256 threads (4 waves),
// 2 x 24KB LDS buffers = 48KB -> 2 blocks/CU. K-accumulation order
// BIT-IDENTICAL to round 0 (sequential chunks, hh/hl/lh MFMA order).
__global__ __launch_bounds__(256, 1) void gemm_conv(
    const ushort* __restrict__ Ahi, const ushort* __restrict__ Alo,
    const ushort* __restrict__ Bhi, const ushort* __restrict__ Blo,
    const float* __restrict__ bias, ushort* __restrict__ outHi,
    ushort* __restrict__ outLo) {
  constexpr int NC = 288;
  constexpr int ASEC = 128 * 32;             // ushorts per A section (8KB)
  constexpr int BSEC = 64 * 32;              // ushorts per B section (4KB)
  constexpr int BUFU = 2 * ASEC + 2 * BSEC;  // 24 KB per buffer
  __shared__ ushort sm[2 * BUFU];            // 48 KB -> 2 blocks/CU
  const int t = threadIdx.x;
  const int m0 = blockIdx.x * 128;
  const int n0 = blockIdx.y * 64;

  const int lane = t & 63, wv = t >> 6;
  const int wm = (wv & 1) * 64, wn = (wv >> 1) * 32;
  const int rA = wm + (lane & 15);
  const int rB = wn + (lane & 15);
  const int segA = (lane >> 4) * 2048;  // A seg region base (bytes)
  const int segB = (lane >> 4) * 1024;  // B seg region base (bytes)

  auto stage = [&](int c, int bufIdx) {
    ushort* secAh = sm + bufIdx * BUFU;
    ushort* secAl = secAh + ASEC;
    ushort* secBh = secAl + ASEC;
    ushort* secBl = secBh + BSEC;
    int off = c >> 5, cc = c & 31;
    int oy = off / 3, ox = off - 3 * oy;
#pragma unroll
    for (int q = 0; q < 2; ++q) {
      int L = t + 256 * q;
      int row = L & 127, seg = L >> 7;
      int m = m0 + row, y = m >> 6, xq = m & 63;
      size_t aoff = ((size_t)(cc * 4 + seg) * 4356 + (y + oy) * 66 + (xq + ox)) * 16;
      gl_lds16((const char*)Ahi + aoff, (char*)secAh + L * 16);
      gl_lds16((const char*)Alo + aoff, (char*)secAl + L * 16);
    }
    {
      int L = t;
      int row = L & 63, seg = L >> 6;
      size_t boff = (((size_t)(off * 32 + cc) * 4 + seg) * 1024 + (n0 + row)) * 16;
      gl_lds16((const char*)Bhi + boff, (char*)secBh + L * 16);
      gl_lds16((const char*)Blo + boff, (char*)secBl + L * 16);
    }
  };

  floatx4 acc[4][2];
#pragma unroll
  for (int i = 0; i < 4; ++i)
#pragma unroll
    for (int j = 0; j < 2; ++j) acc[i][j] = (floatx4){0.f, 0.f, 0.f, 0.f};

  auto compute = [&](const ushort* sb) {
    const char* cAh = (const char*)sb;
    const char* cAl = (const char*)(sb + ASEC);
    const char* cBh = (const char*)(sb + 2 * ASEC);
    const char* cBl = (const char*)(sb + 2 * ASEC + BSEC);
    short8 ah[4], al[4], bh2[2], bl2[2];
#pragma unroll
    for (int i = 0; i < 4; ++i) {
      int pa = segA + (rA + 16 * i) * 16;
      ah[i] = *(const short8*)(cAh + pa);
      al[i] = *(const short8*)(cAl + pa);
    }
#pragma unroll
    for (int j = 0; j < 2; ++j) {
      int pb = segB + (rB + 16 * j) * 16;
      bh2[j] = *(const short8*)(cBh + pb);
      bl2[j] = *(const short8*)(cBl + pb);
    }
#pragma unroll
    for (int i = 0; i < 4; ++i)
#pragma unroll
      for (int j = 0; j < 2; ++j) {
        acc[i][j] = __builtin_amdgcn_mfma_f32_16x16x32_bf16(ah[i], bh2[j], acc[i][j], 0, 0, 0);
        acc[i][j] = __builtin_amdgcn_mfma_f32_16x16x32_bf16(ah[i], bl2[j], acc[i][j], 0, 0, 0);
        acc[i][j] = __builtin_amdgcn_mfma_f32_16x16x32_bf16(al[i], bh2[j], acc[i][j], 0, 0, 0);
      }
  };

  stage(0, 0);
  for (int kc = 0; kc < NC; ++kc) {
    __syncthreads();  // staged chunk kc landed; prev compute's reads done
    if (kc + 1 < NC) stage(kc + 1, (kc + 1) & 1);  // overlap with compute
    compute(sm + (kc & 1) * BUFU);
  }

#pragma unroll
  for (int i = 0; i < 4; ++i)
#pragma unroll
    for (int j = 0; j < 2; ++j) {
      int nn = n0 + wn + 16 * j + (lane & 15);
      float bv = bias[nn];
#pragma unroll
      for (int r = 0; r < 4; ++r) {
        int mm = m0 + wm + 16 * i + (lane >> 4) * 4 + r;  // C: row=(lane>>4)*4+reg
        float v = fmaxf(acc[i][j][r] + bv, 0.f);
        ushort h2 = bf16rne(v);
        float hf = __uint_as_float((uint)h2 << 16);
        ushort l2 = bf16rne(v - hf);
        int cc = nn >> 5, sg = (nn >> 3) & 3, e = nn & 7;
        size_t ho = ((size_t)(cc * 4 + sg) * 4096 + mm) * 8 + e;
        outHi[ho] = h2;
        outLo[ho] = l2;
      }
    }
}

// ---------------- head GEMM + FUSED decode epilogue -------------------------
// Tile 32x128, grid (128,1). A-LDS + B-regs (round 8). After the K loop the
// raw f32 row block [32][128] is staged through LDS and decoded IN-BLOCK
// (identical f32 values -> identical decode math; hist atomics are integer,
// order-independent). Removes the decode_k dispatch + raw round-trip.
__global__ __launch_bounds__(256, 1) void gemm_head_decode(
    const ushort* __restrict__ Ahi, const ushort* __restrict__ Alo,
    const ushort* __restrict__ Bhi, const ushort* __restrict__ Blo,
    const float* __restrict__ bias, float* __restrict__ scores,
    float4* __restrict__ boxes, uint* __restrict__ key32,
    uint* __restrict__ hist) {
  constexpr int BM = 32, BN = 128, NCH = 32;
  constexpr int ASEC = BM * 32;
  constexpr int BUFU = 2 * ASEC;
  constexpr int MI = 2, NJ = 2;  // 4 waves 1x4: wave n-range 32, m-range 32
  __shared__ ushort sm[2 * BUFU];   // 8 KB
  __shared__ float rawT[32][128];   // 16 KB
  const int t = threadIdx.x;
  const int m0 = blockIdx.x * BM;

  const int lane = t & 63, wv = t >> 6;
  const int wn = wv * 32;
  const int rA = lane & 15;
  const int segA = (lane >> 4) * (BM * 16);

  auto stage = [&](int c, int bufIdx) {
    ushort* secAh = sm + bufIdx * BUFU;
    ushort* secAl = secAh + ASEC;
    for (int L = t; L < BM * 4; L += 256) {
      int row = L % BM, seg = L / BM;
      size_t aoff = ((size_t)(c * 4 + seg) * 4096 + (m0 + row)) * 16;
      gl_lds16((const char*)Ahi + aoff, (char*)secAh + L * 16);
      gl_lds16((const char*)Alo + aoff, (char*)secAl + L * 16);
    }
  };

  auto loadB = [&](int c, short8* bh, short8* bl) {
    int sg = lane >> 4;
#pragma unroll
    for (int j = 0; j < NJ; ++j) {
      int co = wn + (lane & 15) + 16 * j;
      size_t boff = (((size_t)(c * 4 + sg)) * 128 + co) * 16;
      bh[j] = *(const short8*)((const char*)Bhi + boff);
      bl[j] = *(const short8*)((const char*)Blo + boff);
    }
  };

  floatx4 acc[MI][NJ];
#pragma unroll
  for (int i = 0; i < MI; ++i)
#pragma unroll
    for (int j = 0; j < NJ; ++j) acc[i][j] = (floatx4){0.f, 0.f, 0.f, 0.f};

  auto compute = [&](const ushort* sb, const short8* bh2, const short8* bl2) {
    const char* cAh = (const char*)sb;
    const char* cAl = (const char*)(sb + ASEC);
    short8 ah[MI], al[MI];
#pragma unroll
    for (int i = 0; i < MI; ++i) {
      int pa = segA + (rA + 16 * i) * 16;
      ah[i] = *(const short8*)(cAh + pa);
      al[i] = *(const short8*)(cAl + pa);
    }
#pragma unroll
    for (int i = 0; i < MI; ++i)
#pragma unroll
      for (int j = 0; j < NJ; ++j) {
        acc[i][j] = __builtin_amdgcn_mfma_f32_16x16x32_bf16(ah[i], bh2[j], acc[i][j], 0, 0, 0);
        acc[i][j] = __builtin_amdgcn_mfma_f32_16x16x32_bf16(ah[i], bl2[j], acc[i][j], 0, 0, 0);
        acc[i][j] = __builtin_amdgcn_mfma_f32_16x16x32_bf16(al[i], bh2[j], acc[i][j], 0, 0, 0);
      }
  };

  short8 b0h[NJ], b0l[NJ], b1h[NJ], b1l[NJ];
  stage(0, 0);
  loadB(0, b0h, b0l);
  for (int kc = 0; kc < NCH; kc += 2) {
    __syncthreads();
    if (kc + 1 < NCH) { stage(kc + 1, 1); loadB(kc + 1, b1h, b1l); }
    compute(sm, b0h, b0l);
    __syncthreads();
    if (kc + 2 < NCH) { stage(kc + 2, 0); loadB(kc + 2, b0h, b0l); }
    compute(sm + BUFU, b1h, b1l);
  }

  // ---- raw tile -> LDS (exact f32 values, same as old global raw) ----
  __syncthreads();  // all waves done reading sm fragments
#pragma unroll
  for (int i = 0; i < MI; ++i)
#pragma unroll
    for (int j = 0; j < NJ; ++j) {
      int nn = wn + 16 * j + (lane & 15);
      float bv = bias[nn];
#pragma unroll
      for (int r = 0; r < 4; ++r) {
        int lm = 16 * i + (lane >> 4) * 4 + r;  // local row 0..31
        rawT[lm][nn] = acc[i][j][r] + bv;
      }
    }
  __syncthreads();

  // ---- fused decode: 32 rows x 15 anchors = 480 items over 256 threads ----
#pragma unroll
  for (int it = 0; it < 2; ++it) {
    int item = it * 256 + t;
    if (item >= 480) break;
    int lm = item / 15, a = item - lm * 15;
    int m = m0 + lm;
    int i = m * 15 + a;
    int y = m >> 6, x = m & 63;
    const float* rp = &rawT[lm][0];
    float logit = rp[a];
    float dx = rp[15 + 4 * a], dy = rp[16 + 4 * a];
    float dw = rp[17 + 4 * a], dh = rp[18 + 4 * a];
    int rr = a / 5, ss = a - rr * 5;
    float sc5 = (float)(2 << ss);
    float W = ((rr == 0) ? 23.f : (rr == 1) ? 16.f : 11.f) * sc5;
    float H = ((rr == 0) ? 12.f : (rr == 1) ? 16.f : 22.f) * sc5;
    float aw = W - 1.f, ah = H - 1.f;
    float ax = x * 16.f + 7.5f, ay = y * 16.f + 7.5f;
    float ox = dx * aw + ax, oyc = dy * ah + ay;
    float ow = expf(fminf(dw, 4.14f)) * aw * 0.5f;
    float oh = expf(fminf(dh, 4.14f)) * ah * 0.5f;
    float x1 = fminf(fmaxf(ox - ow, 0.f), 1023.f);
    float y1 = fminf(fmaxf(oyc - oh, 0.f), 1023.f);
    float x2 = fminf(fmaxf(ox + ow, 0.f), 1023.f);
    float y2 = fminf(fmaxf(oyc + oh, 0.f), 1023.f);
    bool inval = ((x2 - x1) < 16.f) || ((y2 - y1) < 16.f);
    float sc = inval ? -1.f : (1.f / (1.f + expf(-logit)));
    scores[i] = sc;
    boxes[i] = inval ? make_float4(-1.f, -1.f, -1.f, -1.f) : make_float4(x1, y1, x2, y2);
    uint kb = __float_as_uint(sc);
    uint key = (kb & 0x80000000u) ? ~kb : (kb | 0x80000000u);
    key32[i] = key;
    atomicAdd(&hist[key >> 16], 1u);
  }
}

// ---------------- seg_sum: coalesced 256-entry segment sums of hist ---------
__global__ __launch_bounds__(256) void seg_sum(const uint* __restrict__ hist,
                                               uint* __restrict__ segsum) {
  __shared__ uint red[256];
  int b = blockIdx.x, t = threadIdx.x;
  red[t] = hist[b * 256 + t];
  __syncthreads();
  for (int d = 128; d > 0; d >>= 1) {
    if (t < d) red[t] += red[t + d];
    __syncthreads();
  }
  if (t == 0) segsum[b] = red[0];
}

// ---------------- find 16-bit prefix threshold for top-6000 -----------------
__global__ __launch_bounds__(256) void find_t16(const uint* __restrict__ hist,
                                                const uint* __restrict__ segsum,
                                                uint* __restrict__ selT) {
  __shared__ uint ps[256];
  __shared__ int segS;
  int t = threadIdx.x;
  ps[t] = segsum[t];
  __syncthreads();
  for (int d = 1; d < 256; d <<= 1) {
    uint v = ps[t] + ((t + d < 256) ? ps[t + d] : 0u);
    __syncthreads();
    ps[t] = v;
    __syncthreads();
  }
  if (ps[t] >= 6000u && (t == 255 || ps[t + 1] < 6000u)) segS = t;
  __syncthreads();
  int sg = segS;
  uint base = (sg == 255) ? 0u : ps[sg + 1];
  uint h2 = hist[sg * 256 + t];
  __syncthreads();
  ps[t] = h2;
  __syncthreads();
  for (int d = 1; d < 256; d <<= 1) {
    uint v = ps[t] + ((t + d < 256) ? ps[t + d] : 0u);
    __syncthreads();
    ps[t] = v;
    __syncthreads();
  }
  if (base + ps[t] >= 6000u && (t == 255 || base + ps[t + 1] < 6000u))
    *selT = (uint)(sg * 256 + t);
}

// ---------------- gather candidates (prefix >= T16) -------------------------
__global__ __launch_bounds__(256) void gather_k(const uint* __restrict__ key32,
                                                const uint* __restrict__ selT,
                                                uint* __restrict__ cnt,
                                                u64* __restrict__ cand) {
  int i = blockIdx.x * 256 + threadIdx.x;  // exactly 61440
  uint T = *selT;
  uint k = key32[i];
  if ((k >> 16) >= T) {
    uint pos = atomicAdd(cnt, 1u);
    if (pos < 8192) cand[pos] = ((u64)k << 32) | (u64)(~(uint)i);
  }
}

// ---------------- single-block bitonic sort (desc) + gather top-6000 --------
__global__ __launch_bounds__(1024) void sort_gather(
    const u64* __restrict__ cand, const uint* __restrict__ cnt,
    const float* __restrict__ scores, const float4* __restrict__ boxes,
    float* __restrict__ sortedS, float4* __restrict__ sortedB) {
  extern __shared__ u64 sk[];  // 8192 * 8 = 64 KB
  int t = threadIdx.x;
  int C = (int)*cnt;
  if (C > 8192) C = 8192;
  for (int j = t; j < 8192; j += 1024) sk[j] = (j < C) ? cand[j] : 0ull;
  __syncthreads();
  for (int k = 2; k <= 8192; k <<= 1) {
    for (int j2 = k >> 1; j2 > 0; j2 >>= 1) {
      for (int p = t; p < 4096; p += 1024) {
        int i = ((p & ~(j2 - 1)) << 1) | (p & (j2 - 1));
        int ix = i | j2;
        u64 a = sk[i], b = sk[ix];
        bool ddir = (i & k) != 0;
        if ((a < b) != ddir) { sk[i] = b; sk[ix] = a; }
      }
      __syncthreads();
    }
  }
  for (int j = t; j < 6016; j += 1024) {
    if (j < 6000) {
      u64 key = sk[j];
      uint idx = ~(uint)(key & 0xffffffffu);
      sortedS[j] = scores[idx];
      sortedB[j] = boxes[idx];
    } else {
      sortedS[j] = -1.f;
      sortedB[j] = make_float4(0.f, 0.f, 0.f, 0.f);
    }
  }
}

// ---------------- IoU suppression bitmask: mask[row][128 u64 words] ---------
__global__ __launch_bounds__(64) void iou_mask(const float4* __restrict__ boxes,
                                               u64* __restrict__ mask) {
  __shared__ float cx1[64], cy1[64], cx2[64], cy2[64], car[64];
  int bi = blockIdx.x, bj = blockIdx.y, t = threadIdx.x;
  float4 cb = boxes[bj * 64 + t];
  cx1[t] = cb.x; cy1[t] = cb.y; cx2[t] = cb.z; cy2[t] = cb.w;
  car[t] = (cb.z - cb.x) * (cb.w - cb.y);
  __syncthreads();
  int r = bi * 64 + t;
  float4 rb = boxes[r];
  float ra = (rb.z - rb.x) * (rb.w - rb.y);
  u64 wd = 0;
#pragma unroll 8
  for (int j = 0; j < 64; ++j) {
    float iw = fmaxf(fminf(rb.z, cx2[j]) - fmaxf(rb.x, cx1[j]), 0.f);
    float ih = fmaxf(fminf(rb.w, cy2[j]) - fmaxf(rb.y, cy1[j]), 0.f);
    float inter = iw * ih;
    float iou = inter / (ra + car[j] - inter + 1e-12f);
    if (iou > 0.7f && r != bj * 64 + j) wd |= (1ull << j);
  }
  mask[(size_t)r * 128 + bj] = wd;
}

// ---------------- NMS scan: window-parallel resolution ----------------------
// Exact-semantics rewrite of the serial scan. Per 64-row window w2:
//  (1) ONE parallel load: lane c fetches mask[row_c][w2] (the only word
//      needed to resolve suppression WITHIN the window) -- replaces a
//      dependent ~900cy load per pick with one per window.
//  (2) in-register serial resolution via __shfl (identical to serial:
//      candidate j is suppressed by accepted i iff bit j of row_i word w2).
//  (3) accepted picks' full rows OR'd into Sx/Sy with a 4-deep pipeline of
//      INDEPENDENT loads (accepted set already known -> no misspeculation).
// klist order and the 300-stop match the serial scan bit-for-bit.
__global__ __launch_bounds__(64) void nms_scan(const u64* __restrict__ mask,
                                               const float* __restrict__ sortedS,
                                               const float4* __restrict__ sortedB,
                                               float* __restrict__ out) {
  __shared__ int klist[300];
  int lane = threadIdx.x;
  u64 Sx = 0, Sy = 0;  // lane l owns suppression words 2l and 2l+1
  for (int w2 = 0; w2 < 94; ++w2) {
    bool neg = sortedS[w2 * 64 + lane] < 0.f;
    u64 m2 = __ballot(neg);
    if ((w2 >> 1) == lane) { if (w2 & 1) Sy = m2; else Sx = m2; }
  }
  int count = 0;
  for (int w2 = 0; w2 < 94 && count < 300; ++w2) {
    u64 cur = __shfl((w2 & 1) ? Sy : Sx, w2 >> 1);
    u64 rem = ~cur;
    if (w2 == 93) rem &= (1ull << 48) - 1;  // rows 6000..6015 are pad
    if (!rem) continue;
    // (1) window word load: lane c -> row (w2*64+c), word w2
    u64 W = 0;
    if ((rem >> lane) & 1)
      W = mask[(size_t)(w2 * 64 + lane) * 128 + w2];
    // (2) in-register resolution
    u64 acc = 0, live = rem;
    bool full = false;
    while (live) {
      int b = __builtin_ctzll(live);
      acc |= 1ull << b;
      ++count;
      if (count == 300) { full = true; break; }
      u64 wb = __shfl(W, b);
      live &= ~wb;
      live &= (b == 63) ? 0ull : (~0ull << (b + 1));
    }
    if (lane == 0) {
      u64 a2 = acc;
      int idx = count - __builtin_popcountll(acc);
      while (a2) {
        int b = __builtin_ctzll(a2);
        klist[idx++] = w2 * 64 + b;
        a2 &= a2 - 1;
      }
    }
    if (full) break;
    // (3) 4-deep pipelined row-OR of accepted picks
    u64 a2 = acc;
    int r0 = -1, r1 = -1, r2 = -1, r3 = -1;
    ulonglong2 v0, v1, v2, v3;
    if (a2) { int b = __builtin_ctzll(a2); a2 &= a2 - 1; r0 = w2 * 64 + b;
      v0 = ((const ulonglong2*)(mask + (size_t)r0 * 128))[lane]; }
    if (a2) { int b = __builtin_ctzll(a2); a2 &= a2 - 1; r1 = w2 * 64 + b;
      v1 = ((const ulonglong2*)(mask + (size_t)r1 * 128))[lane]; }
    if (a2) { int b = __builtin_ctzll(a2); a2 &= a2 - 1; r2 = w2 * 64 + b;
      v2 = ((const ulonglong2*)(mask + (size_t)r2 * 128))[lane]; }
    if (a2) { int b = __builtin_ctzll(a2); a2 &= a2 - 1; r3 = w2 * 64 + b;
      v3 = ((const ulonglong2*)(mask + (size_t)r3 * 128))[lane]; }
    while (r0 >= 0) {
      Sx |= v0.x;
      Sy |= v0.y;
      r0 = r1; v0 = v1;
      r1 = r2; v1 = v2;
      r2 = r3; v2 = v3;
      r3 = -1;
      if (a2) { int b = __builtin_ctzll(a2); a2 &= a2 - 1; r3 = w2 * 64 + b;
        v3 = ((const ulonglong2*)(mask + (size_t)r3 * 128))[lane]; }
    }
  }
  __syncthreads();
  for (int j = lane; j < 300; j += 64) {
    float s;
    float4 bb;
    if (j < count) {
      int i = klist[j];
      s = sortedS[i];
      bb = sortedB[i];
    } else {
      s = -1.f;
      bb = make_float4(-1.f, -1.f, -1.f, -1.f);
    }
    out[j * 5 + 0] = s;
    out[j * 5 + 1] = bb.x;
    out[j * 5 + 2] = bb.y;
    out[j * 5 + 3] = bb.z;
    out[j * 5 + 4] = bb.w;
  }
}

// ---------------- workspace layout (bytes) ----------------------------------
constexpr size_t O_XH = 0;                // 8,921,088   xpadT hi
constexpr size_t O_XL = 8921088;          // 8,921,088   xpadT lo
constexpr size_t O_WTH = 17842176;        // 18,874,368  wT hi
constexpr size_t O_WTL = 36716544;        // 18,874,368  wT lo
constexpr size_t O_HH = 55590912;         // 8,388,608   h hi
constexpr size_t O_HL = 63979520;         // 8,388,608   h lo
constexpr size_t O_WHH = 72368128;        // 262,144     head w hi
constexpr size_t O_WHL = 72630272;        // 262,144     head w lo
constexpr size_t O_BHD = 72892416;        // 512         head bias
constexpr size_t O_SC = 72892928;         // 245,760     scores
constexpr size_t O_BX = 73138688;         // 983,040     boxes (float4)
constexpr size_t O_KEY = 74121728;        // 245,760     key32
constexpr size_t O_HIST = 74367488;       // 262,144     histogram
constexpr size_t O_CNT = 74629632;        // 256         atomic counter
constexpr size_t O_CAND = 74629888;       // 65,536      candidates
constexpr size_t O_SELT = 74695424;       // 256         T16
constexpr size_t O_SS = 74695680;         // 24,064      sorted scores [6016]
constexpr size_t O_SB = 74719744;         // 96,256      sorted boxes  [6016]
// aliases (regions dead by the time these are written):
constexpr size_t O_MASK = 17842176;       // 6,160,384  NMS mask (aliases wT, dead after conv GEMM)
constexpr size_t O_SEG = 24002560;        // 1,024      segsum (aliases wT tail)
// total distinct footprint ~74.8 MB

extern "C" void kernel_launch(void* const* d_in, const int* in_sizes, int n_in,
                              void* d_out, int out_size, void* d_ws,
                              size_t ws_size, hipStream_t stream) {
  (void)in_sizes; (void)n_in; (void)out_size; (void)ws_size;
  const float* x = (const float*)d_in[1];
  const float* conv_w = (const float*)d_in[2];
  const float* conv_b = (const float*)d_in[3];
  const float* score_w = (const float*)d_in[4];
  const float* score_b = (const float*)d_in[5];
  const float* loc_w = (const float*)d_in[6];
  const float* loc_b = (const float*)d_in[7];
  float* out = (float*)d_out;
  char* ws = (char*)d_ws;

  ushort* xh = (ushort*)(ws + O_XH);
  ushort* xl = (ushort*)(ws + O_XL);
  ushort* wTh = (ushort*)(ws + O_WTH);
  ushort* wTl = (ushort*)(ws + O_WTL);
  ushort* hh = (ushort*)(ws + O_HH);
  ushort* hl = (ushort*)(ws + O_HL);
  ushort* wHh = (ushort*)(ws + O_WHH);
  ushort* wHl = (ushort*)(ws + O_WHL);
  float* biasH = (float*)(ws + O_BHD);
  float* scores = (float*)(ws + O_SC);
  float4* boxes = (float4*)(ws + O_BX);
  uint* key32 = (uint*)(ws + O_KEY);
  uint* hist = (uint*)(ws + O_HIST);
  uint* cnt = (uint*)(ws + O_CNT);
  u64* cand = (u64*)(ws + O_CAND);
  uint* selT = (uint*)(ws + O_SELT);
  float* sortedS = (float*)(ws + O_SS);
  float4* sortedB = (float4*)(ws + O_SB);
  u64* mask = (u64*)(ws + O_MASK);
  uint* segsum = (uint*)(ws + O_SEG);

  // zero the padded-input borders (whole buffer) and histogram+counter
  hipMemsetAsync(ws + O_XH, 0, 2 * 8921088, stream);
  hipMemsetAsync(ws + O_HIST, 0, 262144 + 256, stream);

  prep_x<<<dim3(32, 4, 2), 256, 0, stream>>>(x, xh, xl);
  prep_w<<<dim3(32, 4, 4), 256, 0, stream>>>(conv_w, wTh, wTl);
  prep_head<<<512, 256, 0, stream>>>(score_w, loc_w, score_b, loc_b, wHh, wHl, biasH);

  // conv: M=4096, N=1024, K=9216 -> h (relu, bf16 hi/lo); tile 128x64,
  // grid (32,16)=512 blocks -> 2 blocks/CU; round-7 double-buffer (209us)
  gemm_conv<<<dim3(32, 16), 256, 0, stream>>>(xh, xl, wTh, wTl, conv_b, hh, hl);
  // heads + fused decode: M=4096, N=128(pad), K=1024; tile 32x128, 128 blocks
  gemm_head_decode<<<dim3(128, 1), 256, 0, stream>>>(hh, hl, wHh, wHl, biasH,
                                                     scores, boxes, key32, hist);

  seg_sum<<<256, 256, 0, stream>>>(hist, segsum);
  find_t16<<<1, 256, 0, stream>>>(hist, segsum, selT);
  gather_k<<<240, 256, 0, stream>>>(key32, selT, cnt, cand);
  sort_gather<<<1, 1024, 65536, stream>>>(cand, cnt, scores, boxes, sortedS, sortedB);
  iou_mask<<<dim3(94, 94), 64, 0, stream>>>(sortedB, mask);
  nms_scan<<<1, 64, 0, stream>>>(mask, sortedS, sortedB, out);
}

// Round 12
// 694.139 us; speedup vs baseline: 1.0196x; 1.0078x over previous
//
#include <hip/hip_runtime.h>

typedef unsigned int uint;
typedef unsigned short ushort;
typedef unsigned long long u64;

typedef __attribute__((ext_vector_type(8))) short short8;
typedef __attribute__((ext_vector_type(4))) float floatx4;

// ---------------- helpers ----------------
__device__ inline ushort bf16rne(float v) {
  uint b = __float_as_uint(v);
  uint r = (b + 0x7fffu + ((b >> 16) & 1u)) >> 16;
  return (ushort)r;
}

__device__ inline void gl_lds16(const void* g, void* l) {
  __builtin_amdgcn_global_load_lds(
      (const __attribute__((address_space(1))) unsigned int*)g,
      (__attribute__((address_space(3))) unsigned int*)l, 16, 0, 0);
}

// ======================= chunk-seg-major global layouts =====================
//   xpadT: [cc 32][seg 4][spatial 66*66][8e]   (ci = cc*32 + seg*8 + e)
//   wT:    [off*32+cc][seg 4][co 1024][8e]
//   h:     [cc 32][seg 4][m 4096][8e]
//   wH:    [cc 32][seg 4][o 128][8e]
// Proven: seg-major LDS stage = 0 bank conflicts + coalesced wave staging.
// Conv structure frozen at r7 double-buffer (209-212us best of 4 tried).
// Round 12: pipeline collapsed 13 enqueues -> 6 kernels (prep_all fuses the
// 3 preps + border-zero + hist-zero; topk fuses seg_sum/find_t16/gather/sort).
// With 6 kernels, the top-5 profile necessarily exposes the real tail cost.

// ---------------- prep_all: prep_x (256) | prep_w (512) | prep_head (512) ---
__global__ __launch_bounds__(256) void prep_all(
    const float* __restrict__ x, const float* __restrict__ conv_w,
    const float* __restrict__ score_w, const float* __restrict__ loc_w,
    const float* __restrict__ score_b, const float* __restrict__ loc_b,
    ushort* __restrict__ xh, ushort* __restrict__ xl,
    ushort* __restrict__ wTh, ushort* __restrict__ wTl,
    ushort* __restrict__ wHh, ushort* __restrict__ wHl,
    float* __restrict__ biasH, uint* __restrict__ hist) {
  __shared__ float tile[8][512];  // used by prep_x branch only
  const int b = blockIdx.x, t = threadIdx.x;
  if (b < 256) {
    // ---- prep_x: x -> padded transposed bf16 hi/lo ----
    int cc = b >> 3, sg = (b >> 1) & 3, z = b & 1;
    int ci0 = cc * 32 + sg * 8;
    size_t obase = (size_t)(cc * 4 + sg) * 4356;
    if (z == 0) {  // border cells of this (cc,sg) plane -> zeros (was memset)
      short8 z8 = {};
      for (int k = t; k < 260; k += 256) {
        int s;
        if (k < 66) s = k;                          // row 0
        else if (k < 132) s = 65 * 66 + (k - 66);   // row 65
        else if (k < 196) s = (k - 131) * 66;       // col 0, rows 1..64
        else s = (k - 195) * 66 + 65;               // col 65, rows 1..64
        size_t o = (obase + s) * 8;
        *(short8*)(xh + o) = z8;
        *(short8*)(xl + o) = z8;
      }
    }
    for (int it = 0; it < 4; ++it) {
      int s0 = z * 2048 + it * 512;
#pragma unroll
      for (int e = 0; e < 8; ++e) {
        tile[e][t] = x[(size_t)(ci0 + e) * 4096 + s0 + t];
        tile[e][t + 256] = x[(size_t)(ci0 + e) * 4096 + s0 + 256 + t];
      }
      __syncthreads();
#pragma unroll
      for (int w = 0; w < 2; ++w) {
        int sl = w * 256 + t;
        int s = s0 + sl;
        int y = s >> 6, xx = s & 63;
        short8 sh, slo;
#pragma unroll
        for (int e = 0; e < 8; ++e) {
          float v = tile[e][sl];
          ushort h2 = bf16rne(v);
          float hf = __uint_as_float((uint)h2 << 16);
          sh[e] = (short)h2;
          slo[e] = (short)bf16rne(v - hf);
        }
        size_t o = (obase + (size_t)(y + 1) * 66 + (xx + 1)) * 8;
        *(short8*)(xh + o) = sh;
        *(short8*)(xl + o) = slo;
      }
      __syncthreads();
    }
  } else if (b < 768) {
    // ---- prep_w: conv_w[co][ci][3][3] -> wT chunk-seg-major ----
    int q = b - 256;
    int cc = q >> 4, sg = (q >> 2) & 3, zz = q & 3;
    int e = t & 7, col = t >> 3;
    int ci = cc * 32 + sg * 8 + e;
    for (int chunk = 0; chunk < 8; ++chunk) {
      int co = zz * 256 + chunk * 32 + col;
      const float* src = conv_w + ((size_t)co * 1024 + ci) * 9;
      float v[9];
#pragma unroll
      for (int o = 0; o < 9; ++o) v[o] = src[o];
#pragma unroll
      for (int off = 0; off < 9; ++off) {
        ushort h2 = bf16rne(v[off]);
        float hf = __uint_as_float((uint)h2 << 16);
        ushort l2 = bf16rne(v[off] - hf);
        size_t oi = ((size_t)(off * 32 + cc) * 4 + sg) * 8192 + (size_t)co * 8 + e;
        wTh[oi] = h2;
        wTl[oi] = l2;
      }
    }
  } else {
    // ---- prep_head + hist zeroing ----
    int idx = (b - 768) * 256 + t;  // < 131072
    int o = idx >> 10, ci = idx & 1023;
    float v = 0.f;
    if (o < 15) v = score_w[o * 1024 + ci];
    else if (o < 75) v = loc_w[(o - 15) * 1024 + ci];
    ushort h2 = bf16rne(v);
    float hf = __uint_as_float((uint)h2 << 16);
    int cc = ci >> 5, sg = (ci >> 3) & 3, e = ci & 7;
    size_t oi = ((size_t)(cc * 4 + sg) * 128 + o) * 8 + e;
    wHh[oi] = h2;
    wHl[oi] = bf16rne(v - hf);
    if (idx < 128) biasH[idx] = (idx < 15) ? score_b[idx] : ((idx < 75) ? loc_b[idx - 15] : 0.f);
    if (idx < 65536) hist[idx] = 0u;  // was hipMemsetAsync; ordered before head
  }
}

// ---------------- conv GEMM (im2col): round-7 double-buffer (209us) ---------
// M=4096, N=1024 (BN=64/block), K=9216. Tile 128x64, 256 threads (4 waves),
// 2 x 24KB LDS buffers = 48KB -> 2 blocks/CU. K-accumulation order
// BIT-IDENTICAL to round 0 (sequential chunks, hh/hl/lh MFMA order).
__global__ __launch_bounds__(256, 1) void gemm_conv(
    const ushort* __restrict__ Ahi, const ushort* __restrict__ Alo,
    const ushort* __restrict__ Bhi, const ushort* __restrict__ Blo,
    const float* __restrict__ bias, ushort* __restrict__ outHi,
    ushort* __restrict__ outLo) {
  constexpr int NC = 288;
  constexpr int ASEC = 128 * 32;             // ushorts per A section (8KB)
  constexpr int BSEC = 64 * 32;              // ushorts per B section (4KB)
  constexpr int BUFU = 2 * ASEC + 2 * BSEC;  // 24 KB per buffer
  __shared__ ushort sm[2 * BUFU];            // 48 KB -> 2 blocks/CU
  const int t = threadIdx.x;
  const int m0 = blockIdx.x * 128;
  const int n0 = blockIdx.y * 64;

  const int lane = t & 63, wv = t >> 6;
  const int wm = (wv & 1) * 64, wn = (wv >> 1) * 32;
  const int rA = wm + (lane & 15);
  const int rB = wn + (lane & 15);
  const int segA = (lane >> 4) * 2048;  // A seg region base (bytes)
  const int segB = (lane >> 4) * 1024;  // B seg region base (bytes)

  auto stage = [&](int c, int bufIdx) {
    ushort* secAh = sm + bufIdx * BUFU;
    ushort* secAl = secAh + ASEC;
    ushort* secBh = secAl + ASEC;
    ushort* secBl = secBh + BSEC;
    int off = c >> 5, cc = c & 31;
    int oy = off / 3, ox = off - 3 * oy;
#pragma unroll
    for (int q = 0; q < 2; ++q) {
      int L = t + 256 * q;
      int row = L & 127, seg = L >> 7;
      int m = m0 + row, y = m >> 6, xq = m & 63;
      size_t aoff = ((size_t)(cc * 4 + seg) * 4356 + (y + oy) * 66 + (xq + ox)) * 16;
      gl_lds16((const char*)Ahi + aoff, (char*)secAh + L * 16);
      gl_lds16((const char*)Alo + aoff, (char*)secAl + L * 16);
    }
    {
      int L = t;
      int row = L & 63, seg = L >> 6;
      size_t boff = (((size_t)(off * 32 + cc) * 4 + seg) * 1024 + (n0 + row)) * 16;
      gl_lds16((const char*)Bhi + boff, (char*)secBh + L * 16);
      gl_lds16((const char*)Blo + boff, (char*)secBl + L * 16);
    }
  };

  floatx4 acc[4][2];
#pragma unroll
  for (int i = 0; i < 4; ++i)
#pragma unroll
    for (int j = 0; j < 2; ++j) acc[i][j] = (floatx4){0.f, 0.f, 0.f, 0.f};

  auto compute = [&](const ushort* sb) {
    const char* cAh = (const char*)sb;
    const char* cAl = (const char*)(sb + ASEC);
    const char* cBh = (const char*)(sb + 2 * ASEC);
    const char* cBl = (const char*)(sb + 2 * ASEC + BSEC);
    short8 ah[4], al[4], bh2[2], bl2[2];
#pragma unroll
    for (int i = 0; i < 4; ++i) {
      int pa = segA + (rA + 16 * i) * 16;
      ah[i] = *(const short8*)(cAh + pa);
      al[i] = *(const short8*)(cAl + pa);
    }
#pragma unroll
    for (int j = 0; j < 2; ++j) {
      int pb = segB + (rB + 16 * j) * 16;
      bh2[j] = *(const short8*)(cBh + pb);
      bl2[j] = *(const short8*)(cBl + pb);
    }
#pragma unroll
    for (int i = 0; i < 4; ++i)
#pragma unroll
      for (int j = 0; j < 2; ++j) {
        acc[i][j] = __builtin_amdgcn_mfma_f32_16x16x32_bf16(ah[i], bh2[j], acc[i][j], 0, 0, 0);
        acc[i][j] = __builtin_amdgcn_mfma_f32_16x16x32_bf16(ah[i], bl2[j], acc[i][j], 0, 0, 0);
        acc[i][j] = __builtin_amdgcn_mfma_f32_16x16x32_bf16(al[i], bh2[j], acc[i][j], 0, 0, 0);
      }
  };

  stage(0, 0);
  for (int kc = 0; kc < NC; ++kc) {
    __syncthreads();  // staged chunk kc landed; prev compute's reads done
    if (kc + 1 < NC) stage(kc + 1, (kc + 1) & 1);  // overlap with compute
    compute(sm + (kc & 1) * BUFU);
  }

#pragma unroll
  for (int i = 0; i < 4; ++i)
#pragma unroll
    for (int j = 0; j < 2; ++j) {
      int nn = n0 + wn + 16 * j + (lane & 15);
      float bv = bias[nn];
#pragma unroll
      for (int r = 0; r < 4; ++r) {
        int mm = m0 + wm + 16 * i + (lane >> 4) * 4 + r;  // C: row=(lane>>4)*4+reg
        float v = fmaxf(acc[i][j][r] + bv, 0.f);
        ushort h2 = bf16rne(v);
        float hf = __uint_as_float((uint)h2 << 16);
        ushort l2 = bf16rne(v - hf);
        int cc = nn >> 5, sg = (nn >> 3) & 3, e = nn & 7;
        size_t ho = ((size_t)(cc * 4 + sg) * 4096 + mm) * 8 + e;
        outHi[ho] = h2;
        outLo[ho] = l2;
      }
    }
}

// ---------------- head GEMM + FUSED decode epilogue -------------------------
__global__ __launch_bounds__(256, 1) void gemm_head_decode(
    const ushort* __restrict__ Ahi, const ushort* __restrict__ Alo,
    const ushort* __restrict__ Bhi, const ushort* __restrict__ Blo,
    const float* __restrict__ bias, float* __restrict__ scores,
    float4* __restrict__ boxes, uint* __restrict__ key32,
    uint* __restrict__ hist) {
  constexpr int BM = 32, BN = 128, NCH = 32;
  constexpr int ASEC = BM * 32;
  constexpr int BUFU = 2 * ASEC;
  constexpr int MI = 2, NJ = 2;
  __shared__ ushort sm[2 * BUFU];   // 8 KB
  __shared__ float rawT[32][128];   // 16 KB
  const int t = threadIdx.x;
  const int m0 = blockIdx.x * BM;

  const int lane = t & 63, wv = t >> 6;
  const int wn = wv * 32;
  const int rA = lane & 15;
  const int segA = (lane >> 4) * (BM * 16);

  auto stage = [&](int c, int bufIdx) {
    ushort* secAh = sm + bufIdx * BUFU;
    ushort* secAl = secAh + ASEC;
    for (int L = t; L < BM * 4; L += 256) {
      int row = L % BM, seg = L / BM;
      size_t aoff = ((size_t)(c * 4 + seg) * 4096 + (m0 + row)) * 16;
      gl_lds16((const char*)Ahi + aoff, (char*)secAh + L * 16);
      gl_lds16((const char*)Alo + aoff, (char*)secAl + L * 16);
    }
  };

  auto loadB = [&](int c, short8* bh, short8* bl) {
    int sg = lane >> 4;
#pragma unroll
    for (int j = 0; j < NJ; ++j) {
      int co = wn + (lane & 15) + 16 * j;
      size_t boff = (((size_t)(c * 4 + sg)) * 128 + co) * 16;
      bh[j] = *(const short8*)((const char*)Bhi + boff);
      bl[j] = *(const short8*)((const char*)Blo + boff);
    }
  };

  floatx4 acc[MI][NJ];
#pragma unroll
  for (int i = 0; i < MI; ++i)
#pragma unroll
    for (int j = 0; j < NJ; ++j) acc[i][j] = (floatx4){0.f, 0.f, 0.f, 0.f};

  auto compute = [&](const ushort* sb, const short8* bh2, const short8* bl2) {
    const char* cAh = (const char*)sb;
    const char* cAl = (const char*)(sb + ASEC);
    short8 ah[MI], al[MI];
#pragma unroll
    for (int i = 0; i < MI; ++i) {
      int pa = segA + (rA + 16 * i) * 16;
      ah[i] = *(const short8*)(cAh + pa);
      al[i] = *(const short8*)(cAl + pa);
    }
#pragma unroll
    for (int i = 0; i < MI; ++i)
#pragma unroll
      for (int j = 0; j < NJ; ++j) {
        acc[i][j] = __builtin_amdgcn_mfma_f32_16x16x32_bf16(ah[i], bh2[j], acc[i][j], 0, 0, 0);
        acc[i][j] = __builtin_amdgcn_mfma_f32_16x16x32_bf16(ah[i], bl2[j], acc[i][j], 0, 0, 0);
        acc[i][j] = __builtin_amdgcn_mfma_f32_16x16x32_bf16(al[i], bh2[j], acc[i][j], 0, 0, 0);
      }
  };

  short8 b0h[NJ], b0l[NJ], b1h[NJ], b1l[NJ];
  stage(0, 0);
  loadB(0, b0h, b0l);
  for (int kc = 0; kc < NCH; kc += 2) {
    __syncthreads();
    if (kc + 1 < NCH) { stage(kc + 1, 1); loadB(kc + 1, b1h, b1l); }
    compute(sm, b0h, b0l);
    __syncthreads();
    if (kc + 2 < NCH) { stage(kc + 2, 0); loadB(kc + 2, b0h, b0l); }
    compute(sm + BUFU, b1h, b1l);
  }

  __syncthreads();
#pragma unroll
  for (int i = 0; i < MI; ++i)
#pragma unroll
    for (int j = 0; j < NJ; ++j) {
      int nn = wn + 16 * j + (lane & 15);
      float bv = bias[nn];
#pragma unroll
      for (int r = 0; r < 4; ++r) {
        int lm = 16 * i + (lane >> 4) * 4 + r;
        rawT[lm][nn] = acc[i][j][r] + bv;
      }
    }
  __syncthreads();

#pragma unroll
  for (int it = 0; it < 2; ++it) {
    int item = it * 256 + t;
    if (item >= 480) break;
    int lm = item / 15, a = item - lm * 15;
    int m = m0 + lm;
    int i = m * 15 + a;
    int y = m >> 6, x = m & 63;
    const float* rp = &rawT[lm][0];
    float logit = rp[a];
    float dx = rp[15 + 4 * a], dy = rp[16 + 4 * a];
    float dw = rp[17 + 4 * a], dh = rp[18 + 4 * a];
    int rr = a / 5, ss = a - rr * 5;
    float sc5 = (float)(2 << ss);
    float W = ((rr == 0) ? 23.f : (rr == 1) ? 16.f : 11.f) * sc5;
    float H = ((rr == 0) ? 12.f : (rr == 1) ? 16.f : 22.f) * sc5;
    float aw = W - 1.f, ah = H - 1.f;
    float ax = x * 16.f + 7.5f, ay = y * 16.f + 7.5f;
    float ox = dx * aw + ax, oyc = dy * ah + ay;
    float ow = expf(fminf(dw, 4.14f)) * aw * 0.5f;
    float oh = expf(fminf(dh, 4.14f)) * ah * 0.5f;
    float x1 = fminf(fmaxf(ox - ow, 0.f), 1023.f);
    float y1 = fminf(fmaxf(oyc - oh, 0.f), 1023.f);
    float x2 = fminf(fmaxf(ox + ow, 0.f), 1023.f);
    float y2 = fminf(fmaxf(oyc + oh, 0.f), 1023.f);
    bool inval = ((x2 - x1) < 16.f) || ((y2 - y1) < 16.f);
    float sc = inval ? -1.f : (1.f / (1.f + expf(-logit)));
    scores[i] = sc;
    boxes[i] = inval ? make_float4(-1.f, -1.f, -1.f, -1.f) : make_float4(x1, y1, x2, y2);
    uint kb = __float_as_uint(sc);
    uint key = (kb & 0x80000000u) ? ~kb : (kb | 0x80000000u);
    key32[i] = key;
    atomicAdd(&hist[key >> 16], 1u);
  }
}

// ---------------- topk: seg_sum + find_t16 + gather + bitonic sort ----------
// Single 1024-thread block. Integer-exact port of the 4 separate kernels.
// Candidate gather order differs (LDS atomic vs global atomic) but keys are
// UNIQUE (score bits + index) and the bitonic sort canonicalizes order ->
// bit-identical sortedS/sortedB. (Candidate count <= 8192 for this input,
// same clamp as before.)
__global__ __launch_bounds__(1024) void topk(
    const uint* __restrict__ hist, const uint* __restrict__ key32,
    const float* __restrict__ scores, const float4* __restrict__ boxes,
    float* __restrict__ sortedS, float4* __restrict__ sortedB) {
  __shared__ u64 sk[8192];  // 64 KB
  __shared__ uint p4[1024];
  __shared__ uint ps[256];
  __shared__ int segS;
  __shared__ uint selT, cntL;
  const int t = threadIdx.x;
  // segment sums: thread t sums hist[t*64 .. t*64+63] (uint4 x16)
  uint s = 0;
  const uint4* h4 = (const uint4*)(hist + t * 64);
#pragma unroll 4
  for (int i = 0; i < 16; ++i) {
    uint4 v = h4[i];
    s += v.x + v.y + v.z + v.w;
  }
  p4[t] = s;
  if (t == 0) cntL = 0;
  __syncthreads();
  if (t < 256) ps[t] = p4[4 * t] + p4[4 * t + 1] + p4[4 * t + 2] + p4[4 * t + 3];
  __syncthreads();
  // suffix scan over 256 segment sums
  for (int d = 1; d < 256; d <<= 1) {
    uint v = 0;
    if (t < 256) v = ps[t] + ((t + d < 256) ? ps[t + d] : 0u);
    __syncthreads();
    if (t < 256) ps[t] = v;
    __syncthreads();
  }
  if (t < 256 && ps[t] >= 6000u && (t == 255 || ps[t + 1] < 6000u)) segS = t;
  __syncthreads();
  int sg = segS;
  uint base = (sg == 255) ? 0u : ps[sg + 1];
  uint h2 = (t < 256) ? hist[sg * 256 + t] : 0u;
  __syncthreads();
  if (t < 256) ps[t] = h2;
  __syncthreads();
  for (int d = 1; d < 256; d <<= 1) {
    uint v = 0;
    if (t < 256) v = ps[t] + ((t + d < 256) ? ps[t + d] : 0u);
    __syncthreads();
    if (t < 256) ps[t] = v;
    __syncthreads();
  }
  if (t < 256 && base + ps[t] >= 6000u && (t == 255 || base + ps[t + 1] < 6000u))
    selT = (uint)(sg * 256 + t);
  __syncthreads();
  uint T = selT;
  // gather candidates (prefix >= T) into LDS
  for (int j = 0; j < 60; ++j) {
    int i = j * 1024 + t;  // exactly 61440
    uint k = key32[i];
    if ((k >> 16) >= T) {
      uint pos = atomicAdd(&cntL, 1u);
      if (pos < 8192) sk[pos] = ((u64)k << 32) | (u64)(~(uint)i);
    }
  }
  __syncthreads();
  int C = (int)cntL;
  if (C > 8192) C = 8192;
  for (int j = C + t; j < 8192; j += 1024) sk[j] = 0ull;
  __syncthreads();
  // bitonic sort (desc), identical to sort_gather
  for (int k = 2; k <= 8192; k <<= 1) {
    for (int j2 = k >> 1; j2 > 0; j2 >>= 1) {
      for (int p = t; p < 4096; p += 1024) {
        int i = ((p & ~(j2 - 1)) << 1) | (p & (j2 - 1));
        int ix = i | j2;
        u64 a = sk[i], b2 = sk[ix];
        bool ddir = (i & k) != 0;
        if ((a < b2) != ddir) { sk[i] = b2; sk[ix] = a; }
      }
      __syncthreads();
    }
  }
  for (int j = t; j < 6016; j += 1024) {
    if (j < 6000) {
      u64 key = sk[j];
      uint idx = ~(uint)(key & 0xffffffffu);
      sortedS[j] = scores[idx];
      sortedB[j] = boxes[idx];
    } else {
      sortedS[j] = -1.f;
      sortedB[j] = make_float4(0.f, 0.f, 0.f, 0.f);
    }
  }
}

// ---------------- IoU suppression bitmask: mask[row][128 u64 words] ---------
__global__ __launch_bounds__(64) void iou_mask(const float4* __restrict__ boxes,
                                               u64* __restrict__ mask) {
  __shared__ float cx1[64], cy1[64], cx2[64], cy2[64], car[64];
  int bi = blockIdx.x, bj = blockIdx.y, t = threadIdx.x;
  float4 cb = boxes[bj * 64 + t];
  cx1[t] = cb.x; cy1[t] = cb.y; cx2[t] = cb.z; cy2[t] = cb.w;
  car[t] = (cb.z - cb.x) * (cb.w - cb.y);
  __syncthreads();
  int r = bi * 64 + t;
  float4 rb = boxes[r];
  float ra = (rb.z - rb.x) * (rb.w - rb.y);
  u64 wd = 0;
#pragma unroll 8
  for (int j = 0; j < 64; ++j) {
    float iw = fmaxf(fminf(rb.z, cx2[j]) - fmaxf(rb.x, cx1[j]), 0.f);
    float ih = fmaxf(fminf(rb.w, cy2[j]) - fmaxf(rb.y, cy1[j]), 0.f);
    float inter = iw * ih;
    float iou = inter / (ra + car[j] - inter + 1e-12f);
    if (iou > 0.7f && r != bj * 64 + j) wd |= (1ull << j);
  }
  mask[(size_t)r * 128 + bj] = wd;
}

// ---------------- NMS scan: window-parallel resolution (round 11) -----------
__global__ __launch_bounds__(64) void nms_scan(const u64* __restrict__ mask,
                                               const float* __restrict__ sortedS,
                                               const float4* __restrict__ sortedB,
                                               float* __restrict__ out) {
  __shared__ int klist[300];
  int lane = threadIdx.x;
  u64 Sx = 0, Sy = 0;  // lane l owns suppression words 2l and 2l+1
  for (int w2 = 0; w2 < 94; ++w2) {
    bool neg = sortedS[w2 * 64 + lane] < 0.f;
    u64 m2 = __ballot(neg);
    if ((w2 >> 1) == lane) { if (w2 & 1) Sy = m2; else Sx = m2; }
  }
  int count = 0;
  for (int w2 = 0; w2 < 94 && count < 300; ++w2) {
    u64 cur = __shfl((w2 & 1) ? Sy : Sx, w2 >> 1);
    u64 rem = ~cur;
    if (w2 == 93) rem &= (1ull << 48) - 1;  // rows 6000..6015 are pad
    if (!rem) continue;
    u64 W = 0;
    if ((rem >> lane) & 1)
      W = mask[(size_t)(w2 * 64 + lane) * 128 + w2];
    u64 acc = 0, live = rem;
    bool full = false;
    while (live) {
      int b = __builtin_ctzll(live);
      acc |= 1ull << b;
      ++count;
      if (count == 300) { full = true; break; }
      u64 wb = __shfl(W, b);
      live &= ~wb;
      live &= (b == 63) ? 0ull : (~0ull << (b + 1));
    }
    if (lane == 0) {
      u64 a2 = acc;
      int idx = count - __builtin_popcountll(acc);
      while (a2) {
        int b = __builtin_ctzll(a2);
        klist[idx++] = w2 * 64 + b;
        a2 &= a2 - 1;
      }
    }
    if (full) break;
    u64 a2 = acc;
    int r0 = -1, r1 = -1, r2 = -1, r3 = -1;
    ulonglong2 v0, v1, v2, v3;
    if (a2) { int b = __builtin_ctzll(a2); a2 &= a2 - 1; r0 = w2 * 64 + b;
      v0 = ((const ulonglong2*)(mask + (size_t)r0 * 128))[lane]; }
    if (a2) { int b = __builtin_ctzll(a2); a2 &= a2 - 1; r1 = w2 * 64 + b;
      v1 = ((const ulonglong2*)(mask + (size_t)r1 * 128))[lane]; }
    if (a2) { int b = __builtin_ctzll(a2); a2 &= a2 - 1; r2 = w2 * 64 + b;
      v2 = ((const ulonglong2*)(mask + (size_t)r2 * 128))[lane]; }
    if (a2) { int b = __builtin_ctzll(a2); a2 &= a2 - 1; r3 = w2 * 64 + b;
      v3 = ((const ulonglong2*)(mask + (size_t)r3 * 128))[lane]; }
    while (r0 >= 0) {
      Sx |= v0.x;
      Sy |= v0.y;
      r0 = r1; v0 = v1;
      r1 = r2; v1 = v2;
      r2 = r3; v2 = v3;
      r3 = -1;
      if (a2) { int b = __builtin_ctzll(a2); a2 &= a2 - 1; r3 = w2 * 64 + b;
        v3 = ((const ulonglong2*)(mask + (size_t)r3 * 128))[lane]; }
    }
  }
  __syncthreads();
  for (int j = lane; j < 300; j += 64) {
    float s;
    float4 bb;
    if (j < count) {
      int i = klist[j];
      s = sortedS[i];
      bb = sortedB[i];
    } else {
      s = -1.f;
      bb = make_float4(-1.f, -1.f, -1.f, -1.f);
    }
    out[j * 5 + 0] = s;
    out[j * 5 + 1] = bb.x;
    out[j * 5 + 2] = bb.y;
    out[j * 5 + 3] = bb.z;
    out[j * 5 + 4] = bb.w;
  }
}

// ---------------- workspace layout (bytes) ----------------------------------
constexpr size_t O_XH = 0;                // 8,921,088   xpadT hi
constexpr size_t O_XL = 8921088;          // 8,921,088   xpadT lo
constexpr size_t O_WTH = 17842176;        // 18,874,368  wT hi
constexpr size_t O_WTL = 36716544;        // 18,874,368  wT lo
constexpr size_t O_HH = 55590912;         // 8,388,608   h hi
constexpr size_t O_HL = 63979520;         // 8,388,608   h lo
constexpr size_t O_WHH = 72368128;        // 262,144     head w hi
constexpr size_t O_WHL = 72630272;        // 262,144     head w lo
constexpr size_t O_BHD = 72892416;        // 512         head bias
constexpr size_t O_SC = 72892928;         // 245,760     scores
constexpr size_t O_BX = 73138688;         // 983,040     boxes (float4)
constexpr size_t O_KEY = 74121728;        // 245,760     key32
constexpr size_t O_HIST = 74367488;       // 262,144     histogram
constexpr size_t O_SS = 74695680;         // 24,064      sorted scores [6016]
constexpr size_t O_SB = 74719744;         // 96,256      sorted boxes  [6016]
// aliases (regions dead by the time these are written):
constexpr size_t O_MASK = 17842176;       // 6,160,384  NMS mask (aliases wT, dead after conv GEMM)
// total distinct footprint ~74.8 MB

extern "C" void kernel_launch(void* const* d_in, const int* in_sizes, int n_in,
                              void* d_out, int out_size, void* d_ws,
                              size_t ws_size, hipStream_t stream) {
  (void)in_sizes; (void)n_in; (void)out_size; (void)ws_size;
  const float* x = (const float*)d_in[1];
  const float* conv_w = (const float*)d_in[2];
  const float* conv_b = (const float*)d_in[3];
  const float* score_w = (const float*)d_in[4];
  const float* score_b = (const float*)d_in[5];
  const float* loc_w = (const float*)d_in[6];
  const float* loc_b = (const float*)d_in[7];
  float* out = (float*)d_out;
  char* ws = (char*)d_ws;

  ushort* xh = (ushort*)(ws + O_XH);
  ushort* xl = (ushort*)(ws + O_XL);
  ushort* wTh = (ushort*)(ws + O_WTH);
  ushort* wTl = (ushort*)(ws + O_WTL);
  ushort* hh = (ushort*)(ws + O_HH);
  ushort* hl = (ushort*)(ws + O_HL);
  ushort* wHh = (ushort*)(ws + O_WHH);
  ushort* wHl = (ushort*)(ws + O_WHL);
  float* biasH = (float*)(ws + O_BHD);
  float* scores = (float*)(ws + O_SC);
  float4* boxes = (float4*)(ws + O_BX);
  uint* key32 = (uint*)(ws + O_KEY);
  uint* hist = (uint*)(ws + O_HIST);
  float* sortedS = (float*)(ws + O_SS);
  float4* sortedB = (float4*)(ws + O_SB);
  u64* mask = (u64*)(ws + O_MASK);

  // 1: all preps fused (borders + hist zeroing included; no memsets needed)
  prep_all<<<1280, 256, 0, stream>>>(x, conv_w, score_w, loc_w, score_b, loc_b,
                                     xh, xl, wTh, wTl, wHh, wHl, biasH, hist);
  // 2: conv GEMM (r7 structure, frozen)
  gemm_conv<<<dim3(32, 16), 256, 0, stream>>>(xh, xl, wTh, wTl, conv_b, hh, hl);
  // 3: head GEMM + fused decode
  gemm_head_decode<<<dim3(128, 1), 256, 0, stream>>>(hh, hl, wHh, wHl, biasH,
                                                     scores, boxes, key32, hist);
  // 4: threshold + gather + sort (fused)
  topk<<<1, 1024, 0, stream>>>(hist, key32, scores, boxes, sortedS, sortedB);
  // 5: IoU bitmask
  iou_mask<<<dim3(94, 94), 64, 0, stream>>>(sortedB, mask);
  // 6: NMS scan
  nms_scan<<<1, 64, 0, stream>>>(mask, sortedS, sortedB, out);
}